// Round 7
// baseline (174.238 us; speedup 1.0000x reference)
//
#include <hip/hip_runtime.h>
#include <math.h>

#define BATCH 64
#define CC    256
#define ATTRN 300
#define DD    256
#define HW    784
#define HW4   196   // HW / 4
#define O1    32
#define TF4   49    // float4 columns per tile (4 tiles * 49 * 4 = 784)

// ws layout (floats):
// [16384, 16384+524288)  : corrT [64][256 t][32 o]   (t-major, o contiguous)

// ---------------------------------------------------------------- k2 (fused k1+sketch+circulant)
__global__ __launch_bounds__(512) void k2_fused(
    const float* __restrict__ attr_one_hot,
    const float* __restrict__ W_emb,
    const float* __restrict__ b_emb,
    const int*   __restrict__ h1,
    const float* __restrict__ s1,
    const float* __restrict__ conv1_w,
    float* __restrict__ corrT)
{
    const int b = blockIdx.x, og = blockIdx.y;
    const int tid = threadIdx.x;
    const int t = tid & 255, kh = tid >> 8;   // kh is wave-uniform
    const int o0 = og * 8;

    __shared__ float s_attr[ATTRN];
    __shared__ float s_sx[DD];
    __shared__ float s_w1[8][DD];
    __shared__ float s_part[8][DD];

    if (kh == 0) {
        s_sx[t] = 0.f;
        if (t < 75) {
            float4 a = *(const float4*)(attr_one_hot + b * ATTRN + 4 * t);
            *(float4*)&s_attr[4 * t] = a;
        }
    } else {
#pragma unroll
        for (int j = 0; j < 8; ++j) s_w1[j][t] = conv1_w[(o0 + j) * CC + t];
    }
    __syncthreads();

    if (kh == 0) {
        float acc = b_emb[t];
        const float* wr = W_emb + (size_t)t * ATTRN;   // rows are 1200B = 16B-aligned
#pragma unroll 5
        for (int v = 0; v < 75; ++v) {
            float4 w = *(const float4*)(wr + 4 * v);
            float4 a = *(const float4*)(&s_attr[4 * v]);
            acc += w.x * a.x + w.y * a.y + w.z * a.z + w.w * a.w;
        }
        atomicAdd(&s_sx[h1[t]], s1[t] * acc);
    }
    __syncthreads();

    float acc[8] = {0.f,0.f,0.f,0.f,0.f,0.f,0.f,0.f};
    const int kbase = kh << 7;
    for (int k4 = 0; k4 < 32; ++k4) {
        const int k = kbase + 4 * k4;
        float x0 = s_sx[(k     - t) & 255];
        float x1 = s_sx[(k + 1 - t) & 255];
        float x2 = s_sx[(k + 2 - t) & 255];
        float x3 = s_sx[(k + 3 - t) & 255];
#pragma unroll
        for (int oo = 0; oo < 8; ++oo) {
            float4 w = *(const float4*)&s_w1[oo][k];
            acc[oo] += w.x * x0 + w.y * x1 + w.z * x2 + w.w * x3;
        }
    }
    if (kh == 1) {
#pragma unroll
        for (int oo = 0; oo < 8; ++oo) s_part[oo][t] = acc[oo];
    }
    __syncthreads();
    if (kh == 0) {
        float4 r0, r1;
        r0.x = acc[0] + s_part[0][t]; r0.y = acc[1] + s_part[1][t];
        r0.z = acc[2] + s_part[2][t]; r0.w = acc[3] + s_part[3][t];
        r1.x = acc[4] + s_part[4][t]; r1.y = acc[5] + s_part[5][t];
        r1.z = acc[6] + s_part[6][t]; r1.w = acc[7] + s_part[7][t];
        float4* dst = (float4*)(corrT + ((size_t)b * DD + t) * O1 + o0);
        dst[0] = r0; dst[1] = r1;
    }
}

// ---------------------------------------------------------------- k3
// 1024 threads = 16 waves: 2-way c-half (ch) x 8-way o-quad (oq).
// acc = 4 float4 (16 VGPR) + depth-4 double-buffered prefetch (bufA/bufB,
// 32 VGPR) fits UNDER the allocator's observed 64-VGPR cap (round 6:
// depth-8 + 32-VGPR acc hit the cap and spilled 30MB to scratch).
// 4 global_load_dwordx4 in flight per thread; extra 2x tile re-read
// (8 o-quads vs 4 octets) is L2-absorbed.
#define FMA4(A, S, E) { (A).x += (S)*(E).x; (A).y += (S)*(E).y; (A).z += (S)*(E).z; (A).w += (S)*(E).w; }

__global__ __launch_bounds__(1024, 4) void k3_main(
    const float* __restrict__ ent,
    const float* __restrict__ corrT,
    const int*   __restrict__ h2,
    const float* __restrict__ s2,
    const float* __restrict__ conv2_w,
    float* __restrict__ out_map,
    float* __restrict__ out_feat)
{
    const int b = blockIdx.x, tile = blockIdx.y;
    const int tid  = threadIdx.x;
    const int wv   = tid >> 6, lane = tid & 63;
    const int ch   = wv >> 3;     // c-half: c in [128*ch, 128*ch+128)
    const int oq   = wv & 7;      // o-quad: o in [4*oq, 4*oq+4)

    union SMem {
        float  Pl[CC][36];          // P[c][o], pitch 36 floats (bank spread)
        float4 red[4][TF4][9];      // [slot][f4 loc][4 acc + pad]
    };
    __shared__ SMem sm;
    __shared__ float4 s_amap4[TF4];
    __shared__ float  s_c2[O1];

    // ---- stage P[c][o] = s2[c] * corrT[b][h2[c]][o]; 4 threads per c
    {
        const int c = tid >> 2, qp = tid & 3;
        const int hc = h2[c];
        const float sc = s2[c];
        const float4* src = (const float4*)(corrT + ((size_t)b * DD + hc) * O1);
        float4 x0 = src[2 * qp], x1 = src[2 * qp + 1];
        x0.x *= sc; x0.y *= sc; x0.z *= sc; x0.w *= sc;
        x1.x *= sc; x1.y *= sc; x1.z *= sc; x1.w *= sc;
        *(float4*)&sm.Pl[c][8 * qp]     = x0;
        *(float4*)&sm.Pl[c][8 * qp + 4] = x1;
        if (tid < O1) s_c2[tid] = conv2_w[tid];
    }
    __syncthreads();

    const bool act = lane < TF4;
    const int f4i = tile * TF4 + (act ? lane : TF4 - 1);
    const float4* ent4 = (const float4*)ent;
    const int c0 = ch * 128;

    float4 acc[4];
#pragma unroll
    for (int o = 0; o < 4; ++o) acc[o] = make_float4(0.f, 0.f, 0.f, 0.f);

    const float4* eptr = ent4 + (size_t)(b * CC + c0) * HW4 + f4i;

    float4 bufA[4], bufB[4];
#pragma unroll
    for (int u = 0; u < 4; ++u) bufA[u] = eptr[(size_t)u * HW4];

    for (int cc0 = 0; cc0 < 128; cc0 += 8) {
        // prefetch group at cc0+4 while computing group at cc0
#pragma unroll
        for (int u = 0; u < 4; ++u) bufB[u] = eptr[(size_t)(cc0 + 4 + u) * HW4];
#pragma unroll
        for (int u = 0; u < 4; ++u) {
            const int c = c0 + cc0 + u;
            float4 p = *(const float4*)&sm.Pl[c][4 * oq];
            FMA4(acc[0], p.x, bufA[u]); FMA4(acc[1], p.y, bufA[u]);
            FMA4(acc[2], p.z, bufA[u]); FMA4(acc[3], p.w, bufA[u]);
        }
        // prefetch group at cc0+8 (clamped on last iter) while computing cc0+4
#pragma unroll
        for (int u = 0; u < 4; ++u) {
            int idx = cc0 + 8 + u;
            idx = idx > 127 ? 127 : idx;
            bufA[u] = eptr[(size_t)idx * HW4];
        }
#pragma unroll
        for (int u = 0; u < 4; ++u) {
            const int c = c0 + cc0 + 4 + u;
            float4 p = *(const float4*)&sm.Pl[c][4 * oq];
            FMA4(acc[0], p.x, bufB[u]); FMA4(acc[1], p.y, bufB[u]);
            FMA4(acc[2], p.z, bufB[u]); FMA4(acc[3], p.w, bufB[u]);
        }
    }

    // ---- cross-wave reduce + relu + conv2: pass g covers o in [8g, 8g+8)
    // writers: 4 waves with oq in {2g, 2g+1}, slot = 2*(oq&1)+ch.
    float pre = 0.f;
#pragma unroll
    for (int g = 0; g < 4; ++g) {
        __syncthreads();                 // Pl dead after g=0 entry
        if ((oq >> 1) == g && act) {
            const int slot = 2 * (oq & 1) + ch;
#pragma unroll
            for (int i = 0; i < 4; ++i) sm.red[slot][lane][i] = acc[i];
        }
        __syncthreads();
        if (tid < 4 * TF4) {
            const int fi = tid >> 2, j = tid & 3;
#pragma unroll
            for (int i = 0; i < 4; ++i) {
                float v0 = ((const float*)&sm.red[0][fi][i])[j]
                         + ((const float*)&sm.red[1][fi][i])[j];
                float v1 = ((const float*)&sm.red[2][fi][i])[j]
                         + ((const float*)&sm.red[3][fi][i])[j];
                pre += s_c2[8 * g + i]     * fmaxf(v0, 0.f);
                pre += s_c2[8 * g + 4 + i] * fmaxf(v1, 0.f);
            }
        }
    }
    __syncthreads();
    if (tid < 4 * TF4) {
        const int fi = tid >> 2, j = tid & 3;
        float am = 1.f / (1.f + expf(-pre));
        ((float*)&s_amap4[fi])[j] = am;
        out_map[b * HW + tile * (4 * TF4) + tid] = am;
    }
    __syncthreads();

    // ---- output pass: wave wv covers c in [16*wv, 16*wv+16) — nested inside
    // its GEMM read range [128*ch, 128*ch+128) so re-reads are L1/L2-warm.
    const float4 am4 = s_amap4[act ? lane : 0];
    float4* of4 = (float4*)out_feat;
    const int cb = wv * 16;
#pragma unroll 4
    for (int cc = 0; cc < 16; ++cc) {
        const int c = cb + cc;
        if (act) {
            const size_t idx = (size_t)(b * CC + c) * HW4 + f4i;
            float4 e4 = ent4[idx];
            float4 r;
            r.x = am4.x * e4.x; r.y = am4.y * e4.y;
            r.z = am4.z * e4.z; r.w = am4.w * e4.w;
            of4[idx] = r;
        }
    }
}

extern "C" void kernel_launch(void* const* d_in, const int* in_sizes, int n_in,
                              void* d_out, int out_size, void* d_ws, size_t ws_size,
                              hipStream_t stream) {
    const float* ent   = (const float*)d_in[0];
    const float* attr  = (const float*)d_in[1];
    const float* W_emb = (const float*)d_in[2];
    const float* b_emb = (const float*)d_in[3];
    const int*   h1    = (const int*)d_in[4];
    const float* s1    = (const float*)d_in[5];
    const int*   h2    = (const int*)d_in[6];
    const float* s2    = (const float*)d_in[7];
    const float* c1w   = (const float*)d_in[8];
    const float* c2w   = (const float*)d_in[9];

    float* ws    = (float*)d_ws;
    float* corrT = ws + 16384;

    float* out      = (float*)d_out;
    float* out_map  = out;                 // [64,1,28,28]
    float* out_feat = out + BATCH * HW;    // [64,256,28,28]

    hipLaunchKernelGGL(k2_fused, dim3(BATCH, 4), dim3(512), 0, stream,
                       attr, W_emb, b_emb, h1, s1, c1w, corrT);
    hipLaunchKernelGGL(k3_main, dim3(BATCH, 4), dim3(1024), 0, stream,
                       ent, corrT, h2, s2, c2w, out_map, out_feat);
}

// Round 8
// 148.790 us; speedup vs baseline: 1.1710x; 1.1710x over previous
//
#include <hip/hip_runtime.h>
#include <math.h>

#define BATCH 64
#define CC    256
#define ATTRN 300
#define DD    256
#define HW    784
#define HW4   196   // HW / 4
#define O1    32
#define TF4   49    // float4 columns per tile (4 tiles * 49 * 4 = 784)

// ws layout (floats):
// [16384, 16384+524288)  : corrT [64][256 t][32 o]   (t-major, o contiguous)

// ---------------------------------------------------------------- k2 (fused k1+sketch+circulant)
__global__ __launch_bounds__(512) void k2_fused(
    const float* __restrict__ attr_one_hot,
    const float* __restrict__ W_emb,
    const float* __restrict__ b_emb,
    const int*   __restrict__ h1,
    const float* __restrict__ s1,
    const float* __restrict__ conv1_w,
    float* __restrict__ corrT)
{
    const int b = blockIdx.x, og = blockIdx.y;
    const int tid = threadIdx.x;
    const int t = tid & 255, kh = tid >> 8;   // kh is wave-uniform
    const int o0 = og * 8;

    __shared__ float s_attr[ATTRN];
    __shared__ float s_sx[DD];
    __shared__ float s_w1[8][DD];
    __shared__ float s_part[8][DD];

    if (kh == 0) {
        s_sx[t] = 0.f;
        if (t < 75) {
            float4 a = *(const float4*)(attr_one_hot + b * ATTRN + 4 * t);
            *(float4*)&s_attr[4 * t] = a;
        }
    } else {
#pragma unroll
        for (int j = 0; j < 8; ++j) s_w1[j][t] = conv1_w[(o0 + j) * CC + t];
    }
    __syncthreads();

    if (kh == 0) {
        float acc = b_emb[t];
        const float* wr = W_emb + (size_t)t * ATTRN;   // rows are 1200B = 16B-aligned
#pragma unroll 5
        for (int v = 0; v < 75; ++v) {
            float4 w = *(const float4*)(wr + 4 * v);
            float4 a = *(const float4*)(&s_attr[4 * v]);
            acc += w.x * a.x + w.y * a.y + w.z * a.z + w.w * a.w;
        }
        atomicAdd(&s_sx[h1[t]], s1[t] * acc);
    }
    __syncthreads();

    float acc[8] = {0.f,0.f,0.f,0.f,0.f,0.f,0.f,0.f};
    const int kbase = kh << 7;
    for (int k4 = 0; k4 < 32; ++k4) {
        const int k = kbase + 4 * k4;
        float x0 = s_sx[(k     - t) & 255];
        float x1 = s_sx[(k + 1 - t) & 255];
        float x2 = s_sx[(k + 2 - t) & 255];
        float x3 = s_sx[(k + 3 - t) & 255];
#pragma unroll
        for (int oo = 0; oo < 8; ++oo) {
            float4 w = *(const float4*)&s_w1[oo][k];
            acc[oo] += w.x * x0 + w.y * x1 + w.z * x2 + w.w * x3;
        }
    }
    if (kh == 1) {
#pragma unroll
        for (int oo = 0; oo < 8; ++oo) s_part[oo][t] = acc[oo];
    }
    __syncthreads();
    if (kh == 0) {
        float4 r0, r1;
        r0.x = acc[0] + s_part[0][t]; r0.y = acc[1] + s_part[1][t];
        r0.z = acc[2] + s_part[2][t]; r0.w = acc[3] + s_part[3][t];
        r1.x = acc[4] + s_part[4][t]; r1.y = acc[5] + s_part[5][t];
        r1.z = acc[6] + s_part[6][t]; r1.w = acc[7] + s_part[7][t];
        float4* dst = (float4*)(corrT + ((size_t)b * DD + t) * O1 + o0);
        dst[0] = r0; dst[1] = r1;
    }
}

// ---------------------------------------------------------------- k3
// 16 waves = 4 ci (c-range) x 4 oi (o-octet), round-2 proven decomposition.
// ent staged to LDS via __builtin_amdgcn_global_load_lds (width 16):
// per ci-group, 8 chunks of 8 rows (1 row = 64 lanes x 16B = 1KB, linear).
// Chunk k+1 issued before compute(k); barrier vmcnt-drain covered by
// ~4x560cy of per-SIMD compute. Rounds 3/6/7 proved hipcc sinks register
// prefetch buffers (VGPR 36/64-spill/44); LDS staging bypasses VGPRs.
// Dynamic LDS: Pl 36,864B + stage 65,536B = 102,400B; red aliases stage.
#define FMA4(A, S, E) { (A).x += (S)*(E).x; (A).y += (S)*(E).y; (A).z += (S)*(E).z; (A).w += (S)*(E).w; }

#define PL_OFF 0        // Pl[c][j] = lds[c*36 + j], 9216 floats (pitch 36 = 144B, 16B-mult)
#define ST_OFF 9216     // stage[ci][q][cc][lane]: ci*4096 + q*2048 + cc*256 + 4*lane (floats)

__device__ __forceinline__ void gld_lds16(const float4* g, float* l) {
    __builtin_amdgcn_global_load_lds(
        (__attribute__((address_space(1))) void*)g,
        (__attribute__((address_space(3))) void*)l,
        16, 0, 0);
}

__global__ __launch_bounds__(1024, 1) void k3_main(
    const float* __restrict__ ent,
    const float* __restrict__ corrT,
    const int*   __restrict__ h2,
    const float* __restrict__ s2,
    const float* __restrict__ conv2_w,
    float* __restrict__ out_map,
    float* __restrict__ out_feat)
{
    extern __shared__ float lds[];
    const int b = blockIdx.x, tile = blockIdx.y;
    const int tid  = threadIdx.x;
    const int wv   = tid >> 6, lane = tid & 63;
    const int ci   = wv >> 2;     // c-split: c in [64*ci, 64*ci+64)
    const int oi   = wv & 3;      // o-octet: o in [8*oi, 8*oi+8)

    __shared__ float4 s_amap4[TF4];
    __shared__ float  s_c2[O1];

    const bool act = lane < TF4;
    const int lclamp = act ? lane : (TF4 - 1);
    const int f4i = tile * TF4 + lclamp;
    const float4* ent4 = (const float4*)ent;
    const int c0 = ci * 64;
    // per-lane global base for this wave's ci-range, lane-clamped (same
    // semantics as the old direct loads: inactive lanes duplicate f4 48)
    const float4* gbase = ent4 + (size_t)(b * CC + c0) * HW4 + tile * TF4 + lclamp;

    // ---- prologue: issue chunk 0 stage (overlaps with Pl staging below)
    {
        const int rr0 = 2 * oi;
        float* d0 = &lds[ST_OFF + ci * 4096 + 0 * 2048 + rr0 * 256];
        gld_lds16(gbase + (size_t)(rr0)     * HW4, d0);
        gld_lds16(gbase + (size_t)(rr0 + 1) * HW4, d0 + 256);
    }

    // ---- stage P[c][o] = s2[c] * corrT[b][h2[c]][o]; 4 threads per c
    {
        const int c = tid >> 2, qp = tid & 3;
        const int hc = h2[c];
        const float sc = s2[c];
        const float4* src = (const float4*)(corrT + ((size_t)b * DD + hc) * O1);
        float4 x0 = src[2 * qp], x1 = src[2 * qp + 1];
        x0.x *= sc; x0.y *= sc; x0.z *= sc; x0.w *= sc;
        x1.x *= sc; x1.y *= sc; x1.z *= sc; x1.w *= sc;
        *(float4*)&lds[PL_OFF + c * 36 + 8 * qp]     = x0;
        *(float4*)&lds[PL_OFF + c * 36 + 8 * qp + 4] = x1;
        if (tid < O1) s_c2[tid] = conv2_w[tid];
    }
    __syncthreads();   // drains chunk-0 stage + Pl writes

    float4 acc[8];
#pragma unroll
    for (int o = 0; o < 8; ++o) acc[o] = make_float4(0.f, 0.f, 0.f, 0.f);

    // ---- GEMM: 8 chunks of 8 channels, double-buffered LDS staging
    for (int k = 0; k < 8; ++k) {
        if (k < 7) {
            const int rr0 = 2 * oi;
            float* d0 = &lds[ST_OFF + ci * 4096 + ((k + 1) & 1) * 2048 + rr0 * 256];
            gld_lds16(gbase + (size_t)((k + 1) * 8 + rr0)     * HW4, d0);
            gld_lds16(gbase + (size_t)((k + 1) * 8 + rr0 + 1) * HW4, d0 + 256);
        }
        const float* sb = &lds[ST_OFF + ci * 4096 + (k & 1) * 2048 + 4 * lane];
#pragma unroll
        for (int cc = 0; cc < 8; ++cc) {
            const int c = c0 + k * 8 + cc;
            float4 e4 = *(const float4*)(sb + cc * 256);
            float4 pa = *(const float4*)&lds[PL_OFF + c * 36 + 8 * oi];
            float4 pb = *(const float4*)&lds[PL_OFF + c * 36 + 8 * oi + 4];
            FMA4(acc[0], pa.x, e4); FMA4(acc[1], pa.y, e4);
            FMA4(acc[2], pa.z, e4); FMA4(acc[3], pa.w, e4);
            FMA4(acc[4], pb.x, e4); FMA4(acc[5], pb.y, e4);
            FMA4(acc[6], pb.z, e4); FMA4(acc[7], pb.w, e4);
        }
        __syncthreads();   // chunk k reads done; chunk k+1 stage landed
    }

    // ---- cross-wave reduce + relu + conv2, one o-octet per pass
    // red[4][TF4][9] float4 aliases the (dead) stage region
    float4* red = (float4*)&lds[ST_OFF];
    float pre = 0.f;
#pragma unroll
    for (int g = 0; g < 4; ++g) {
        __syncthreads();
        if (oi == g && act) {
#pragma unroll
            for (int i = 0; i < 8; ++i) red[(ci * TF4 + lane) * 9 + i] = acc[i];
        }
        __syncthreads();
        if (tid < 4 * TF4) {
            const int fi = tid >> 2, j = tid & 3;
#pragma unroll
            for (int i = 0; i < 8; ++i) {
                float v = ((const float*)&red[(0 * TF4 + fi) * 9 + i])[j]
                        + ((const float*)&red[(1 * TF4 + fi) * 9 + i])[j]
                        + ((const float*)&red[(2 * TF4 + fi) * 9 + i])[j]
                        + ((const float*)&red[(3 * TF4 + fi) * 9 + i])[j];
                pre += s_c2[8 * g + i] * fmaxf(v, 0.f);
            }
        }
    }
    __syncthreads();
    if (tid < 4 * TF4) {
        const int fi = tid >> 2, j = tid & 3;
        float am = 1.f / (1.f + expf(-pre));
        ((float*)&s_amap4[fi])[j] = am;
        out_map[b * HW + tile * (4 * TF4) + tid] = am;
    }
    __syncthreads();

    // ---- output pass: wave wv covers c in [16*wv, 16*wv+16) — L2/L3-warm
    const float4 am4 = s_amap4[act ? lane : 0];
    float4* of4 = (float4*)out_feat;
    const int cb = wv * 16;
#pragma unroll 4
    for (int cc = 0; cc < 16; ++cc) {
        const int c = cb + cc;
        if (act) {
            const size_t idx = (size_t)(b * CC + c) * HW4 + f4i;
            float4 e4 = ent4[idx];
            float4 r;
            r.x = am4.x * e4.x; r.y = am4.y * e4.y;
            r.z = am4.z * e4.z; r.w = am4.w * e4.w;
            of4[idx] = r;
        }
    }
}

extern "C" void kernel_launch(void* const* d_in, const int* in_sizes, int n_in,
                              void* d_out, int out_size, void* d_ws, size_t ws_size,
                              hipStream_t stream) {
    const float* ent   = (const float*)d_in[0];
    const float* attr  = (const float*)d_in[1];
    const float* W_emb = (const float*)d_in[2];
    const float* b_emb = (const float*)d_in[3];
    const int*   h1    = (const int*)d_in[4];
    const float* s1    = (const float*)d_in[5];
    const int*   h2    = (const int*)d_in[6];
    const float* s2    = (const float*)d_in[7];
    const float* c1w   = (const float*)d_in[8];
    const float* c2w   = (const float*)d_in[9];

    float* ws    = (float*)d_ws;
    float* corrT = ws + 16384;

    float* out      = (float*)d_out;
    float* out_map  = out;                 // [64,1,28,28]
    float* out_feat = out + BATCH * HW;    // [64,256,28,28]

    hipLaunchKernelGGL(k2_fused, dim3(BATCH, 4), dim3(512), 0, stream,
                       attr, W_emb, b_emb, h1, s1, c1w, corrT);
    hipLaunchKernelGGL(k3_main, dim3(BATCH, 4), dim3(1024),
                       (9216 + 16384) * sizeof(float), stream,
                       ent, corrT, h2, s2, c2w, out_map, out_feat);
}